// Round 1
// baseline (529.222 us; speedup 1.0000x reference)
//
#include <hip/hip_runtime.h>
#include <math.h>

#define F_IN 256
#define OUT  64
#define LEAKY 0.2f

// ---------------- GEMM h = x@W, fused f1 = h@a1+b1, f2 = h@a2+b2 ----------------
__global__ __launch_bounds__(256) void gemm_f12_kernel(
    const float* __restrict__ x, const float* __restrict__ W,
    const float* __restrict__ a1, const float* __restrict__ b1,
    const float* __restrict__ a2, const float* __restrict__ b2,
    float* __restrict__ h, float* __restrict__ f1, float* __restrict__ f2,
    int N)
{
    __shared__ float Wl[F_IN * OUT];   // 64 KB
    int t = threadIdx.x;
    for (int i = t * 4; i < F_IN * OUT; i += 256 * 4) {
        *(float4*)&Wl[i] = *(const float4*)&W[i];
    }
    __syncthreads();

    const int wave = t >> 6;
    const int lane = t & 63;
    const int nodeBase = blockIdx.x * 16 + wave * 4;   // 4 nodes per wave

    // clamped row bases (safe loads for tail)
    size_t r0 = (size_t)min(nodeBase + 0, N - 1) * F_IN;
    size_t r1 = (size_t)min(nodeBase + 1, N - 1) * F_IN;
    size_t r2 = (size_t)min(nodeBase + 2, N - 1) * F_IN;
    size_t r3 = (size_t)min(nodeBase + 3, N - 1) * F_IN;

    float acc0 = 0.f, acc1 = 0.f, acc2 = 0.f, acc3 = 0.f;
    for (int k = 0; k < F_IN; k += 4) {
        float4 x0 = *(const float4*)&x[r0 + k];
        float4 x1 = *(const float4*)&x[r1 + k];
        float4 x2 = *(const float4*)&x[r2 + k];
        float4 x3 = *(const float4*)&x[r3 + k];
        float w0 = Wl[(k + 0) * OUT + lane];
        float w1 = Wl[(k + 1) * OUT + lane];
        float w2 = Wl[(k + 2) * OUT + lane];
        float w3 = Wl[(k + 3) * OUT + lane];
        acc0 += x0.x * w0 + x0.y * w1 + x0.z * w2 + x0.w * w3;
        acc1 += x1.x * w0 + x1.y * w1 + x1.z * w2 + x1.w * w3;
        acc2 += x2.x * w0 + x2.y * w1 + x2.z * w2 + x2.w * w3;
        acc3 += x3.x * w0 + x3.y * w1 + x3.z * w2 + x3.w * w3;
    }

    float A1 = a1[lane], A2 = a2[lane];
    float B1 = b1[0],    B2 = b2[0];
    float accs[4] = {acc0, acc1, acc2, acc3};
#pragma unroll
    for (int m = 0; m < 4; ++m) {
        int n = nodeBase + m;
        if (n < N) {
            float hv = accs[m];
            h[(size_t)n * OUT + lane] = hv;
            float s1 = hv * A1, s2 = hv * A2;
            for (int off = 32; off > 0; off >>= 1) {
                s1 += __shfl_down(s1, off);
                s2 += __shfl_down(s2, off);
            }
            if (lane == 0) { f1[n] = s1 + B1; f2[n] = s2 + B2; }
        }
    }
}

// ---------------- CSR build ----------------
__global__ void count_kernel(const int* __restrict__ src, int* __restrict__ counts, int E)
{
    int e = blockIdx.x * 256 + threadIdx.x;
    if (e < E) atomicAdd(&counts[src[e]], 1);
}

// block-of-1024 partial sums
__global__ __launch_bounds__(256) void scan_reduce_kernel(const int* __restrict__ counts,
                                                          int* __restrict__ partials, int N)
{
    int t = threadIdx.x, lane = t & 63, wave = t >> 6;
    int base = blockIdx.x * 1024 + t * 4;
    int s = 0;
#pragma unroll
    for (int i = 0; i < 4; ++i)
        if (base + i < N) s += counts[base + i];
    for (int off = 32; off > 0; off >>= 1) s += __shfl_down(s, off);
    __shared__ int wsum[4];
    if (lane == 0) wsum[wave] = s;
    __syncthreads();
    if (t == 0) partials[blockIdx.x] = wsum[0] + wsum[1] + wsum[2] + wsum[3];
}

// exclusive-scan the partials in one wave (chunks of 128)
__global__ void scan_partials_kernel(int* __restrict__ p, int n)
{
    int lane = threadIdx.x & 63;
    int run = 0;
    for (int base = 0; base < n; base += 128) {
        int o0 = (base + lane      < n) ? p[base + lane]      : 0;
        int o1 = (base + 64 + lane < n) ? p[base + 64 + lane] : 0;
        int v0 = o0, v1 = o1;
        for (int off = 1; off < 64; off <<= 1) { int u = __shfl_up(v0, off); if (lane >= off) v0 += u; }
        int tot0 = __shfl(v0, 63);
        for (int off = 1; off < 64; off <<= 1) { int u = __shfl_up(v1, off); if (lane >= off) v1 += u; }
        v1 += tot0;
        int tot1 = __shfl(v1, 63);
        if (base + lane      < n) p[base + lane]      = run + v0 - o0;
        if (base + 64 + lane < n) p[base + 64 + lane] = run + v1 - o1;
        run += tot1;
    }
}

__global__ __launch_bounds__(256) void scan_final_kernel(const int* __restrict__ counts,
                                                         const int* __restrict__ partials,
                                                         int* __restrict__ row_start, int N)
{
    int t = threadIdx.x, lane = t & 63, wave = t >> 6;
    int base = blockIdx.x * 1024 + t * 4;
    int c0 = (base + 0 < N) ? counts[base + 0] : 0;
    int c1 = (base + 1 < N) ? counts[base + 1] : 0;
    int c2 = (base + 2 < N) ? counts[base + 2] : 0;
    int c3 = (base + 3 < N) ? counts[base + 3] : 0;
    int tsum = c0 + c1 + c2 + c3;
    int incl = tsum;
    for (int off = 1; off < 64; off <<= 1) { int u = __shfl_up(incl, off); if (lane >= off) incl += u; }
    __shared__ int wtot[4];
    if (lane == 63) wtot[wave] = incl;
    __syncthreads();
    int woff = 0;
    for (int w0 = 0; w0 < wave; ++w0) woff += wtot[w0];
    int run = incl - tsum + woff + partials[blockIdx.x];
    if (base + 0 < N) { row_start[base + 0] = run; run += c0; }
    if (base + 1 < N) { row_start[base + 1] = run; run += c1; }
    if (base + 2 < N) { row_start[base + 2] = run; run += c2; }
    if (base + 3 < N) { row_start[base + 3] = run; run += c3; }
}

__global__ void scatter_kernel(const int* __restrict__ src, const int* __restrict__ dst,
                               const int* __restrict__ row_start, int* __restrict__ cursor,
                               int* __restrict__ csr_dst, int E)
{
    int e = blockIdx.x * 256 + threadIdx.x;
    if (e >= E) return;
    int s = src[e];
    int pos = atomicAdd(&cursor[s], 1);
    csr_dst[row_start[s] + pos] = dst[e];
}

// ---------------- online-softmax aggregation: one wave per node ----------------
__global__ __launch_bounds__(256) void aggregate_kernel(
    const float* __restrict__ h, const float* __restrict__ f1, const float* __restrict__ f2,
    const int* __restrict__ row_start, const int* __restrict__ counts,
    const int* __restrict__ csr_dst, const float* __restrict__ out_bias,
    float* __restrict__ out, int N)
{
    int gw   = (blockIdx.x * 256 + threadIdx.x) >> 6;   // one wave per node
    int lane = threadIdx.x & 63;
    if (gw >= N) return;
    int n    = gw;
    int base = row_start[n];
    int deg  = counts[n];
    float f1n  = f1[n];
    float bias = out_bias[lane];

    float m = -INFINITY, den = 0.f, acc = 0.f;
    int dnext = (deg > 0) ? csr_dst[base] : 0;
    for (int i = 0; i < deg; ++i) {
        int d = dnext;
        if (i + 1 < deg) dnext = csr_dst[base + i + 1];
        float hv = h[(size_t)d * OUT + lane];    // coalesced 256B row gather
        float e  = f1n + f2[d];
        e = (e > 0.f) ? e : LEAKY * e;
        float mn = fmaxf(m, e);
        float sc = __expf(m - mn);               // exp(-inf)=0 on first iter
        float p  = __expf(e - mn);
        den = den * sc + p;
        acc = acc * sc + p * hv;
        m = mn;
    }
    float v = (deg > 0) ? (acc / den) : 0.f;
    v += bias;
    out[(size_t)n * OUT + lane] = (v > 0.f) ? v : (__expf(v) - 1.f);
}

extern "C" void kernel_launch(void* const* d_in, const int* in_sizes, int n_in,
                              void* d_out, int out_size, void* d_ws, size_t ws_size,
                              hipStream_t stream)
{
    const float* x        = (const float*)d_in[0];
    const float* W        = (const float*)d_in[1];
    const float* a1       = (const float*)d_in[2];
    const float* b1       = (const float*)d_in[3];
    const float* a2       = (const float*)d_in[4];
    const float* b2       = (const float*)d_in[5];
    const float* out_bias = (const float*)d_in[6];
    const int*   esrc     = (const int*)d_in[7];
    const int*   edst     = (const int*)d_in[8];
    const int N = in_sizes[0] / F_IN;
    const int E = in_sizes[7];
    float* out = (float*)d_out;

    // workspace carve-up (256B aligned)
    char* wsp = (char*)d_ws;
    size_t off = 0;
    auto alloc = [&](size_t bytes) -> void* {
        void* p = wsp + off;
        off = (off + bytes + 255) & ~(size_t)255;
        return p;
    };
    float* h         = (float*)alloc((size_t)N * OUT * sizeof(float));
    float* f1        = (float*)alloc((size_t)N * sizeof(float));
    float* f2        = (float*)alloc((size_t)N * sizeof(float));
    int*   counts    = (int*)alloc((size_t)N * sizeof(int));
    int*   cursor    = (int*)alloc((size_t)N * sizeof(int));
    int*   row_start = (int*)alloc((size_t)N * sizeof(int));
    int    nsb       = (N + 1023) / 1024;
    int*   partials  = (int*)alloc((size_t)nsb * sizeof(int));
    int*   csr_dst   = (int*)alloc((size_t)E * sizeof(int));

    hipMemsetAsync(counts, 0, (size_t)N * sizeof(int), stream);
    hipMemsetAsync(cursor, 0, (size_t)N * sizeof(int), stream);

    gemm_f12_kernel<<<(N + 15) / 16, 256, 0, stream>>>(x, W, a1, b1, a2, b2, h, f1, f2, N);
    count_kernel<<<(E + 255) / 256, 256, 0, stream>>>(esrc, counts, E);
    scan_reduce_kernel<<<nsb, 256, 0, stream>>>(counts, partials, N);
    scan_partials_kernel<<<1, 64, 0, stream>>>(partials, nsb);
    scan_final_kernel<<<nsb, 256, 0, stream>>>(counts, partials, row_start, N);
    scatter_kernel<<<(E + 255) / 256, 256, 0, stream>>>(esrc, edst, row_start, cursor, csr_dst, E);
    aggregate_kernel<<<(N + 3) / 4, 256, 0, stream>>>(h, f1, f2, row_start, counts, csr_dst,
                                                      out_bias, out, N);
}

// Round 2
// 383.666 us; speedup vs baseline: 1.3794x; 1.3794x over previous
//
#include <hip/hip_runtime.h>
#include <math.h>

#define F_IN 256
#define OUT  64
#define LEAKY 0.2f

__device__ __forceinline__ void gload_lds16(const float* g, float* l) {
    __builtin_amdgcn_global_load_lds((const __attribute__((address_space(1))) void*)g,
                                     (__attribute__((address_space(3))) void*)l, 16, 0, 0);
}

// ---------------- GEMM h = x@W, fused f1 = h@a1+b1, f2 = h@a2+b2 ----------------
// 1024 threads = 16 waves; W (64KB) shared in LDS; per-wave-private x tile staged
// via global_load_lds (coalesced -> broadcast layout transform). 8 nodes/wave.
__global__ __launch_bounds__(1024) void gemm_f12_kernel(
    const float* __restrict__ x, const float* __restrict__ W,
    const float* __restrict__ a1, const float* __restrict__ b1,
    const float* __restrict__ a2, const float* __restrict__ b2,
    float* __restrict__ h, float* __restrict__ f1, float* __restrict__ f2,
    int N)
{
    __shared__ float Wl[F_IN * OUT];   // 64 KB
    __shared__ float xl[128 * 32];     // 16 KB: 16 waves x (8 rows x 32 k)
    const int t = threadIdx.x;
    const int wave = t >> 6;
    const int lane = t & 63;

    for (int i = t * 4; i < F_IN * OUT; i += 1024 * 4)
        *(float4*)&Wl[i] = *(const float4*)&W[i];

    const int nodeBase = blockIdx.x * 128 + wave * 8;

    // staging map: lane l -> row (l>>3) of this wave's 8 rows, k-offset (l&7)*4
    int srow = nodeBase + (lane >> 3);
    if (srow > N - 1) srow = N - 1;
    const float* gsrc = x + (size_t)srow * F_IN + ((lane & 7) << 2);
    float* ldst = &xl[wave * 256];     // wave-uniform LDS base; HW adds lane*16B

    float acc[8] = {0.f, 0.f, 0.f, 0.f, 0.f, 0.f, 0.f, 0.f};

    __syncthreads();                   // W ready

    for (int kc = 0; kc < F_IN; kc += 32) {
        // WAR: previous chunk's ds_reads fully retired before overwrite
        asm volatile("s_waitcnt lgkmcnt(0)" ::: "memory");
        gload_lds16(gsrc + kc, ldst);
        asm volatile("s_waitcnt vmcnt(0)" ::: "memory");
#pragma unroll
        for (int kk = 0; kk < 32; kk += 4) {
            float w0 = Wl[(kc + kk + 0) * OUT + lane];
            float w1 = Wl[(kc + kk + 1) * OUT + lane];
            float w2 = Wl[(kc + kk + 2) * OUT + lane];
            float w3 = Wl[(kc + kk + 3) * OUT + lane];
#pragma unroll
            for (int m = 0; m < 8; ++m) {
                float4 xv = *(float4*)&xl[wave * 256 + m * 32 + kk];  // broadcast read
                acc[m] += xv.x * w0 + xv.y * w1 + xv.z * w2 + xv.w * w3;
            }
        }
    }

    float A1 = a1[lane], A2 = a2[lane];
    float B1 = b1[0],    B2 = b2[0];
#pragma unroll
    for (int m = 0; m < 8; ++m) {
        int n = nodeBase + m;
        if (n < N) {
            float hv = acc[m];
            h[(size_t)n * OUT + lane] = hv;
            float s1 = hv * A1, s2 = hv * A2;
            for (int off = 32; off > 0; off >>= 1) {
                s1 += __shfl_down(s1, off);
                s2 += __shfl_down(s2, off);
            }
            if (lane == 0) { f1[n] = s1 + B1; f2[n] = s2 + B2; }
        }
    }
}

// ---------------- CSR build ----------------
__global__ void count_kernel(const int* __restrict__ src, int* __restrict__ counts, int E)
{
    int e = blockIdx.x * 256 + threadIdx.x;
    if (e < E) atomicAdd(&counts[src[e]], 1);
}

__global__ __launch_bounds__(256) void scan_reduce_kernel(const int* __restrict__ counts,
                                                          int* __restrict__ partials, int N)
{
    int t = threadIdx.x, lane = t & 63, wave = t >> 6;
    int base = blockIdx.x * 1024 + t * 4;
    int s = 0;
#pragma unroll
    for (int i = 0; i < 4; ++i)
        if (base + i < N) s += counts[base + i];
    for (int off = 32; off > 0; off >>= 1) s += __shfl_down(s, off);
    __shared__ int wsum[4];
    if (lane == 0) wsum[wave] = s;
    __syncthreads();
    if (t == 0) partials[blockIdx.x] = wsum[0] + wsum[1] + wsum[2] + wsum[3];
}

__global__ void scan_partials_kernel(int* __restrict__ p, int n)
{
    int lane = threadIdx.x & 63;
    int run = 0;
    for (int base = 0; base < n; base += 128) {
        int o0 = (base + lane      < n) ? p[base + lane]      : 0;
        int o1 = (base + 64 + lane < n) ? p[base + 64 + lane] : 0;
        int v0 = o0, v1 = o1;
        for (int off = 1; off < 64; off <<= 1) { int u = __shfl_up(v0, off); if (lane >= off) v0 += u; }
        int tot0 = __shfl(v0, 63);
        for (int off = 1; off < 64; off <<= 1) { int u = __shfl_up(v1, off); if (lane >= off) v1 += u; }
        v1 += tot0;
        int tot1 = __shfl(v1, 63);
        if (base + lane      < n) p[base + lane]      = run + v0 - o0;
        if (base + 64 + lane < n) p[base + 64 + lane] = run + v1 - o1;
        run += tot1;
    }
}

__global__ __launch_bounds__(256) void scan_final_kernel(const int* __restrict__ counts,
                                                         const int* __restrict__ partials,
                                                         int* __restrict__ row_start, int N)
{
    int t = threadIdx.x, lane = t & 63, wave = t >> 6;
    int base = blockIdx.x * 1024 + t * 4;
    int c0 = (base + 0 < N) ? counts[base + 0] : 0;
    int c1 = (base + 1 < N) ? counts[base + 1] : 0;
    int c2 = (base + 2 < N) ? counts[base + 2] : 0;
    int c3 = (base + 3 < N) ? counts[base + 3] : 0;
    int tsum = c0 + c1 + c2 + c3;
    int incl = tsum;
    for (int off = 1; off < 64; off <<= 1) { int u = __shfl_up(incl, off); if (lane >= off) incl += u; }
    __shared__ int wtot[4];
    if (lane == 63) wtot[wave] = incl;
    __syncthreads();
    int woff = 0;
    for (int w0 = 0; w0 < wave; ++w0) woff += wtot[w0];
    int run = incl - tsum + woff + partials[blockIdx.x];
    if (base + 0 < N) { row_start[base + 0] = run; run += c0; }
    if (base + 1 < N) { row_start[base + 1] = run; run += c1; }
    if (base + 2 < N) { row_start[base + 2] = run; run += c2; }
    if (base + 3 < N) { row_start[base + 3] = run; run += c3; }
}

__global__ void scatter_kernel(const int* __restrict__ src, const int* __restrict__ dst,
                               const int* __restrict__ row_start, int* __restrict__ cursor,
                               int* __restrict__ csr_dst, int E)
{
    int e = blockIdx.x * 256 + threadIdx.x;
    if (e >= E) return;
    int s = src[e];
    int pos = atomicAdd(&cursor[s], 1);
    csr_dst[row_start[s] + pos] = dst[e];
}

// ---------------- online-softmax aggregation: one wave per node, 4-wide MLP ----------------
__global__ __launch_bounds__(256) void aggregate_kernel(
    const float* __restrict__ h, const float* __restrict__ f1, const float* __restrict__ f2,
    const int* __restrict__ row_start, const int* __restrict__ counts,
    const int* __restrict__ csr_dst, const float* __restrict__ out_bias,
    float* __restrict__ out, int N)
{
    int gw   = (blockIdx.x * 256 + threadIdx.x) >> 6;
    int lane = threadIdx.x & 63;
    if (gw >= N) return;
    int base = row_start[gw];
    int deg  = counts[gw];
    float f1n  = f1[gw];

    float m = -INFINITY, den = 0.f, acc = 0.f;
    int i = 0;
    for (; i + 4 <= deg; i += 4) {
        int d0 = csr_dst[base + i + 0];
        int d1 = csr_dst[base + i + 1];
        int d2 = csr_dst[base + i + 2];
        int d3 = csr_dst[base + i + 3];
        float hv0 = h[(size_t)d0 * OUT + lane];
        float hv1 = h[(size_t)d1 * OUT + lane];
        float hv2 = h[(size_t)d2 * OUT + lane];
        float hv3 = h[(size_t)d3 * OUT + lane];
        float e0 = f1n + f2[d0]; e0 = (e0 > 0.f) ? e0 : LEAKY * e0;
        float e1 = f1n + f2[d1]; e1 = (e1 > 0.f) ? e1 : LEAKY * e1;
        float e2 = f1n + f2[d2]; e2 = (e2 > 0.f) ? e2 : LEAKY * e2;
        float e3 = f1n + f2[d3]; e3 = (e3 > 0.f) ? e3 : LEAKY * e3;
        float cm = fmaxf(fmaxf(e0, e1), fmaxf(e2, e3));
        float mn = fmaxf(m, cm);
        float sc = __expf(m - mn);           // exp(-inf)=0 on first chunk
        float p0 = __expf(e0 - mn);
        float p1 = __expf(e1 - mn);
        float p2 = __expf(e2 - mn);
        float p3 = __expf(e3 - mn);
        den = den * sc + (p0 + p1) + (p2 + p3);
        acc = acc * sc + p0 * hv0 + p1 * hv1 + p2 * hv2 + p3 * hv3;
        m = mn;
    }
    for (; i < deg; ++i) {
        int d = csr_dst[base + i];
        float hv = h[(size_t)d * OUT + lane];
        float e  = f1n + f2[d];
        e = (e > 0.f) ? e : LEAKY * e;
        float mn = fmaxf(m, e);
        float sc = __expf(m - mn);
        float p  = __expf(e - mn);
        den = den * sc + p;
        acc = acc * sc + p * hv;
        m = mn;
    }
    float v = (deg > 0) ? (acc / den) : 0.f;
    v += out_bias[lane];
    out[(size_t)gw * OUT + lane] = (v > 0.f) ? v : (__expf(v) - 1.f);
}

extern "C" void kernel_launch(void* const* d_in, const int* in_sizes, int n_in,
                              void* d_out, int out_size, void* d_ws, size_t ws_size,
                              hipStream_t stream)
{
    const float* x        = (const float*)d_in[0];
    const float* W        = (const float*)d_in[1];
    const float* a1       = (const float*)d_in[2];
    const float* b1       = (const float*)d_in[3];
    const float* a2       = (const float*)d_in[4];
    const float* b2       = (const float*)d_in[5];
    const float* out_bias = (const float*)d_in[6];
    const int*   esrc     = (const int*)d_in[7];
    const int*   edst     = (const int*)d_in[8];
    const int N = in_sizes[0] / F_IN;
    const int E = in_sizes[7];
    float* out = (float*)d_out;

    char* wsp = (char*)d_ws;
    size_t off = 0;
    auto alloc = [&](size_t bytes) -> void* {
        void* p = wsp + off;
        off = (off + bytes + 255) & ~(size_t)255;
        return p;
    };
    float* h         = (float*)alloc((size_t)N * OUT * sizeof(float));
    float* f1        = (float*)alloc((size_t)N * sizeof(float));
    float* f2        = (float*)alloc((size_t)N * sizeof(float));
    int*   counts    = (int*)alloc((size_t)N * sizeof(int));
    int*   cursor    = (int*)alloc((size_t)N * sizeof(int));
    int*   row_start = (int*)alloc((size_t)N * sizeof(int));
    int    nsb       = (N + 1023) / 1024;
    int*   partials  = (int*)alloc((size_t)nsb * sizeof(int));
    int*   csr_dst   = (int*)alloc((size_t)E * sizeof(int));

    hipMemsetAsync(counts, 0, (size_t)N * sizeof(int), stream);
    hipMemsetAsync(cursor, 0, (size_t)N * sizeof(int), stream);

    gemm_f12_kernel<<<(N + 127) / 128, 1024, 0, stream>>>(x, W, a1, b1, a2, b2, h, f1, f2, N);
    count_kernel<<<(E + 255) / 256, 256, 0, stream>>>(esrc, counts, E);
    scan_reduce_kernel<<<nsb, 256, 0, stream>>>(counts, partials, N);
    scan_partials_kernel<<<1, 64, 0, stream>>>(partials, nsb);
    scan_final_kernel<<<nsb, 256, 0, stream>>>(counts, partials, row_start, N);
    scatter_kernel<<<(E + 255) / 256, 256, 0, stream>>>(esrc, edst, row_start, cursor, csr_dst, E);
    aggregate_kernel<<<(N + 3) / 4, 256, 0, stream>>>(h, f1, f2, row_start, counts, csr_dst,
                                                      out_bias, out, N);
}

// Round 3
// 285.483 us; speedup vs baseline: 1.8538x; 1.3439x over previous
//
#include <hip/hip_runtime.h>
#include <math.h>

#define F_IN 256
#define OUT  64
#define LEAKY 0.2f

typedef __attribute__((ext_vector_type(4))) float f32x4;
typedef __attribute__((ext_vector_type(8))) __bf16 bf16x8;
typedef __attribute__((ext_vector_type(4))) unsigned int u32x4;

__device__ __forceinline__ unsigned cvt_pk_bf16(float lo, float hi) {
    unsigned r;
    asm volatile("v_cvt_pk_bf16_f32 %0, %1, %2" : "=v"(r) : "v"(lo), "v"(hi));
    return r;
}

__device__ __forceinline__ void gload_lds16(const float* g, float* l) {
    __builtin_amdgcn_global_load_lds((const __attribute__((address_space(1))) void*)g,
                                     (__attribute__((address_space(3))) void*)l, 16, 0, 0);
}

// ---------------- MFMA GEMM h = x@W (bf16 in, fp32 acc), fused f1/f2 ----------------
// 256 thr = 4 waves; block tile 128 rows x 64 cols; wave tile 32 rows (2 msub x 4 nsub).
// W: LDS bf16 transposed [col][k], XOR-swizzled.  x: fp32 LDS tile [128][32], double-buffered,
// staged via global_load_lds(16B) with pre-swizzled global source (rule #21).
__global__ __launch_bounds__(256) void gemm_f12_kernel(
    const float* __restrict__ x, const float* __restrict__ W,
    const float* __restrict__ a1, const float* __restrict__ b1,
    const float* __restrict__ a2, const float* __restrict__ b2,
    float* __restrict__ h, float* __restrict__ f1, float* __restrict__ f2,
    int N)
{
    __shared__ __align__(16) unsigned int Wt[64 * 128];   // 64 cols x 256 k bf16 = 32 KB
    __shared__ __align__(16) float xs[2][128 * 32];       // 2 x 16 KB

    const int t    = threadIdx.x;
    const int wave = t >> 6;
    const int lane = t & 63;
    const int rowB = blockIdx.x * 128;

    // ---- stage W -> Wt[c][k] bf16, granule(8k)=16B, slot g holds global granule g^(c&7) ----
    for (int p = t; p < 64 * 32; p += 256) {
        int c = p & 63, g = p >> 6;
        float f[8];
#pragma unroll
        for (int j = 0; j < 8; ++j) f[j] = W[(g * 8 + j) * 64 + c];
        u32x4 d;
        d.x = cvt_pk_bf16(f[0], f[1]);
        d.y = cvt_pk_bf16(f[2], f[3]);
        d.z = cvt_pk_bf16(f[4], f[5]);
        d.w = cvt_pk_bf16(f[6], f[7]);
        int gs = g ^ (c & 7);
        *(u32x4*)&Wt[c * 128 + gs * 4] = d;
    }

    // ---- x staging: tile [128 rows][32 k]; row = 8 granules; LDS linear, source pre-swizzled ----
    auto stage = [&](int buf, int kc) {
#pragma unroll
        for (int i = 0; i < 4; ++i) {
            int row  = i * 32 + wave * 8 + (lane >> 3);   // LDS tile row 0..127
            int g    = lane & 7;
            int srow = rowB + row; if (srow > N - 1) srow = N - 1;
            int gsw  = g ^ (row & 7);
            const float* src = x + (size_t)srow * F_IN + kc + gsw * 4;
            gload_lds16(src, &xs[buf][i * 1024 + wave * 256]);  // + lane*16B by HW
        }
    };

    f32x4 acc[2][4];
#pragma unroll
    for (int m = 0; m < 2; ++m)
#pragma unroll
        for (int n = 0; n < 4; ++n) acc[m][n] = (f32x4){0.f, 0.f, 0.f, 0.f};

    stage(0, 0);
    asm volatile("s_waitcnt vmcnt(0)" ::: "memory");
    __syncthreads();                                      // Wt + xs[0] ready

    for (int ks = 0; ks < 8; ++ks) {
        int cur = ks & 1;
        if (ks < 7) stage(cur ^ 1, (ks + 1) * 32);

        // B frags for this k-step (k = ks*32 + (lane>>4)*8 + j), col = nsub*16 + (lane&15)
        bf16x8 bfrag[4];
#pragma unroll
        for (int ns = 0; ns < 4; ++ns) {
            int c = ns * 16 + (lane & 15);
            int G = ks * 4 + (lane >> 4);
            u32x4 bw = *(u32x4*)&Wt[c * 128 + ((G ^ (c & 7)) << 2)];
            bfrag[ns] = __builtin_bit_cast(bf16x8, bw);
        }
#pragma unroll
        for (int ms = 0; ms < 2; ++ms) {
            int wrow = wave * 32 + ms * 16 + (lane & 15);
            int g0   = (lane >> 4) * 2;
            float4 xa = *(float4*)&xs[cur][wrow * 32 + (((g0 + 0) ^ (wrow & 7)) << 2)];
            float4 xb = *(float4*)&xs[cur][wrow * 32 + (((g0 + 1) ^ (wrow & 7)) << 2)];
            u32x4 ad;
            ad.x = cvt_pk_bf16(xa.x, xa.y);
            ad.y = cvt_pk_bf16(xa.z, xa.w);
            ad.z = cvt_pk_bf16(xb.x, xb.y);
            ad.w = cvt_pk_bf16(xb.z, xb.w);
            bf16x8 afrag = __builtin_bit_cast(bf16x8, ad);
#pragma unroll
            for (int ns = 0; ns < 4; ++ns)
                acc[ms][ns] = __builtin_amdgcn_mfma_f32_16x16x32_bf16(afrag, bfrag[ns],
                                                                      acc[ms][ns], 0, 0, 0);
        }
        asm volatile("s_waitcnt vmcnt(0)" ::: "memory");
        __syncthreads();
    }

    // ---- epilogue: store h; fused f1/f2 (C/D layout: col=lane&15, row=(lane>>4)*4+r) ----
    float A1v[4], A2v[4];
#pragma unroll
    for (int ns = 0; ns < 4; ++ns) {
        A1v[ns] = a1[ns * 16 + (lane & 15)];
        A2v[ns] = a2[ns * 16 + (lane & 15)];
    }
    float B1 = b1[0], B2 = b2[0];
#pragma unroll
    for (int ms = 0; ms < 2; ++ms) {
#pragma unroll
        for (int r = 0; r < 4; ++r) {
            int grow = rowB + wave * 32 + ms * 16 + ((lane >> 4) << 2) + r;
            float s1 = 0.f, s2 = 0.f;
#pragma unroll
            for (int ns = 0; ns < 4; ++ns) {
                float v = acc[ms][ns][r];
                if (grow < N) h[(size_t)grow * OUT + ns * 16 + (lane & 15)] = v;
                s1 += v * A1v[ns];
                s2 += v * A2v[ns];
            }
#pragma unroll
            for (int off = 1; off < 16; off <<= 1) {
                s1 += __shfl_xor(s1, off);
                s2 += __shfl_xor(s2, off);
            }
            if ((lane & 15) == 0 && grow < N) { f1[grow] = s1 + B1; f2[grow] = s2 + B2; }
        }
    }
}

// ---------------- CSR build ----------------
__global__ void count_kernel(const int* __restrict__ src, int* __restrict__ counts, int E)
{
    int e = blockIdx.x * 256 + threadIdx.x;
    if (e < E) atomicAdd(&counts[src[e]], 1);
}

__global__ __launch_bounds__(256) void scan_reduce_kernel(const int* __restrict__ counts,
                                                          int* __restrict__ partials, int N)
{
    int t = threadIdx.x, lane = t & 63, wave = t >> 6;
    int base = blockIdx.x * 1024 + t * 4;
    int s = 0;
#pragma unroll
    for (int i = 0; i < 4; ++i)
        if (base + i < N) s += counts[base + i];
    for (int off = 32; off > 0; off >>= 1) s += __shfl_down(s, off);
    __shared__ int wsum[4];
    if (lane == 0) wsum[wave] = s;
    __syncthreads();
    if (t == 0) partials[blockIdx.x] = wsum[0] + wsum[1] + wsum[2] + wsum[3];
}

__global__ void scan_partials_kernel(int* __restrict__ p, int n)
{
    int lane = threadIdx.x & 63;
    int run = 0;
    for (int base = 0; base < n; base += 128) {
        int o0 = (base + lane      < n) ? p[base + lane]      : 0;
        int o1 = (base + 64 + lane < n) ? p[base + 64 + lane] : 0;
        int v0 = o0, v1 = o1;
        for (int off = 1; off < 64; off <<= 1) { int u = __shfl_up(v0, off); if (lane >= off) v0 += u; }
        int tot0 = __shfl(v0, 63);
        for (int off = 1; off < 64; off <<= 1) { int u = __shfl_up(v1, off); if (lane >= off) v1 += u; }
        v1 += tot0;
        int tot1 = __shfl(v1, 63);
        if (base + lane      < n) p[base + lane]      = run + v0 - o0;
        if (base + 64 + lane < n) p[base + 64 + lane] = run + v1 - o1;
        run += tot1;
    }
}

__global__ __launch_bounds__(256) void scan_final_kernel(const int* __restrict__ counts,
                                                         const int* __restrict__ partials,
                                                         int* __restrict__ row_start, int N)
{
    int t = threadIdx.x, lane = t & 63, wave = t >> 6;
    int base = blockIdx.x * 1024 + t * 4;
    int c0 = (base + 0 < N) ? counts[base + 0] : 0;
    int c1 = (base + 1 < N) ? counts[base + 1] : 0;
    int c2 = (base + 2 < N) ? counts[base + 2] : 0;
    int c3 = (base + 3 < N) ? counts[base + 3] : 0;
    int tsum = c0 + c1 + c2 + c3;
    int incl = tsum;
    for (int off = 1; off < 64; off <<= 1) { int u = __shfl_up(incl, off); if (lane >= off) incl += u; }
    __shared__ int wtot[4];
    if (lane == 63) wtot[wave] = incl;
    __syncthreads();
    int woff = 0;
    for (int w0 = 0; w0 < wave; ++w0) woff += wtot[w0];
    int run = incl - tsum + woff + partials[blockIdx.x];
    if (base + 0 < N) { row_start[base + 0] = run; run += c0; }
    if (base + 1 < N) { row_start[base + 1] = run; run += c1; }
    if (base + 2 < N) { row_start[base + 2] = run; run += c2; }
    if (base + 3 < N) { row_start[base + 3] = run; run += c3; }
}

__global__ void scatter_kernel(const int* __restrict__ src, const int* __restrict__ dst,
                               const int* __restrict__ row_start, int* __restrict__ cursor,
                               int* __restrict__ csr_dst, int E)
{
    int e = blockIdx.x * 256 + threadIdx.x;
    if (e >= E) return;
    int s = src[e];
    int pos = atomicAdd(&cursor[s], 1);
    csr_dst[row_start[s] + pos] = dst[e];
}

// ---------------- online-softmax aggregation: one wave per node, 4-wide MLP ----------------
__global__ __launch_bounds__(256) void aggregate_kernel(
    const float* __restrict__ h, const float* __restrict__ f1, const float* __restrict__ f2,
    const int* __restrict__ row_start, const int* __restrict__ counts,
    const int* __restrict__ csr_dst, const float* __restrict__ out_bias,
    float* __restrict__ out, int N)
{
    int gw   = (blockIdx.x * 256 + threadIdx.x) >> 6;
    int lane = threadIdx.x & 63;
    if (gw >= N) return;
    int base = row_start[gw];
    int deg  = counts[gw];
    float f1n  = f1[gw];

    float m = -INFINITY, den = 0.f, acc = 0.f;
    int i = 0;
    for (; i + 4 <= deg; i += 4) {
        int d0 = csr_dst[base + i + 0];
        int d1 = csr_dst[base + i + 1];
        int d2 = csr_dst[base + i + 2];
        int d3 = csr_dst[base + i + 3];
        float hv0 = h[(size_t)d0 * OUT + lane];
        float hv1 = h[(size_t)d1 * OUT + lane];
        float hv2 = h[(size_t)d2 * OUT + lane];
        float hv3 = h[(size_t)d3 * OUT + lane];
        float e0 = f1n + f2[d0]; e0 = (e0 > 0.f) ? e0 : LEAKY * e0;
        float e1 = f1n + f2[d1]; e1 = (e1 > 0.f) ? e1 : LEAKY * e1;
        float e2 = f1n + f2[d2]; e2 = (e2 > 0.f) ? e2 : LEAKY * e2;
        float e3 = f1n + f2[d3]; e3 = (e3 > 0.f) ? e3 : LEAKY * e3;
        float cm = fmaxf(fmaxf(e0, e1), fmaxf(e2, e3));
        float mn = fmaxf(m, cm);
        float sc = __expf(m - mn);
        float p0 = __expf(e0 - mn);
        float p1 = __expf(e1 - mn);
        float p2 = __expf(e2 - mn);
        float p3 = __expf(e3 - mn);
        den = den * sc + (p0 + p1) + (p2 + p3);
        acc = acc * sc + p0 * hv0 + p1 * hv1 + p2 * hv2 + p3 * hv3;
        m = mn;
    }
    for (; i < deg; ++i) {
        int d = csr_dst[base + i];
        float hv = h[(size_t)d * OUT + lane];
        float e  = f1n + f2[d];
        e = (e > 0.f) ? e : LEAKY * e;
        float mn = fmaxf(m, e);
        float sc = __expf(m - mn);
        float p  = __expf(e - mn);
        den = den * sc + p;
        acc = acc * sc + p * hv;
        m = mn;
    }
    float v = (deg > 0) ? (acc / den) : 0.f;
    v += out_bias[lane];
    out[(size_t)gw * OUT + lane] = (v > 0.f) ? v : (__expf(v) - 1.f);
}

extern "C" void kernel_launch(void* const* d_in, const int* in_sizes, int n_in,
                              void* d_out, int out_size, void* d_ws, size_t ws_size,
                              hipStream_t stream)
{
    const float* x        = (const float*)d_in[0];
    const float* W        = (const float*)d_in[1];
    const float* a1       = (const float*)d_in[2];
    const float* b1       = (const float*)d_in[3];
    const float* a2       = (const float*)d_in[4];
    const float* b2       = (const float*)d_in[5];
    const float* out_bias = (const float*)d_in[6];
    const int*   esrc     = (const int*)d_in[7];
    const int*   edst     = (const int*)d_in[8];
    const int N = in_sizes[0] / F_IN;
    const int E = in_sizes[7];
    float* out = (float*)d_out;

    char* wsp = (char*)d_ws;
    size_t off = 0;
    auto alloc = [&](size_t bytes) -> void* {
        void* p = wsp + off;
        off = (off + bytes + 255) & ~(size_t)255;
        return p;
    };
    float* h         = (float*)alloc((size_t)N * OUT * sizeof(float));
    float* f1        = (float*)alloc((size_t)N * sizeof(float));
    float* f2        = (float*)alloc((size_t)N * sizeof(float));
    int*   counts    = (int*)alloc((size_t)N * sizeof(int));
    int*   cursor    = (int*)alloc((size_t)N * sizeof(int));
    int*   row_start = (int*)alloc((size_t)N * sizeof(int));
    int    nsb       = (N + 1023) / 1024;
    int*   partials  = (int*)alloc((size_t)nsb * sizeof(int));
    int*   csr_dst   = (int*)alloc((size_t)E * sizeof(int));

    hipMemsetAsync(counts, 0, (size_t)N * sizeof(int), stream);
    hipMemsetAsync(cursor, 0, (size_t)N * sizeof(int), stream);

    gemm_f12_kernel<<<(N + 127) / 128, 256, 0, stream>>>(x, W, a1, b1, a2, b2, h, f1, f2, N);
    count_kernel<<<(E + 255) / 256, 256, 0, stream>>>(esrc, counts, E);
    scan_reduce_kernel<<<nsb, 256, 0, stream>>>(counts, partials, N);
    scan_partials_kernel<<<1, 64, 0, stream>>>(partials, nsb);
    scan_final_kernel<<<nsb, 256, 0, stream>>>(counts, partials, row_start, N);
    scatter_kernel<<<(E + 255) / 256, 256, 0, stream>>>(esrc, edst, row_start, cursor, csr_dst, E);
    aggregate_kernel<<<(N + 3) / 4, 256, 0, stream>>>(h, f1, f2, row_start, counts, csr_dst,
                                                      out_bias, out, N);
}

// Round 4
// 204.137 us; speedup vs baseline: 2.5925x; 1.3985x over previous
//
#include <hip/hip_runtime.h>
#include <math.h>

#define F_IN 256
#define OUT  64
#define LEAKY 0.2f

typedef __attribute__((ext_vector_type(4))) float f32x4;
typedef __attribute__((ext_vector_type(8))) __bf16 bf16x8;
typedef __attribute__((ext_vector_type(4))) unsigned int u32x4;

__device__ __forceinline__ unsigned cvt_pk_bf16(float lo, float hi) {
    unsigned r;
    asm volatile("v_cvt_pk_bf16_f32 %0, %1, %2" : "=v"(r) : "v"(lo), "v"(hi));
    return r;
}

__device__ __forceinline__ float bf16bits_to_f32(unsigned short u) {
    return __builtin_bit_cast(float, (unsigned)u << 16);
}

__device__ __forceinline__ void gload_lds16(const float* g, float* l) {
    __builtin_amdgcn_global_load_lds((const __attribute__((address_space(1))) void*)g,
                                     (__attribute__((address_space(3))) void*)l, 16, 0, 0);
}

// ---------------- MFMA GEMM h = x@W (bf16 in, fp32 acc), fused f1/f2; h stored bf16 ----------------
__global__ __launch_bounds__(256) void gemm_f12_kernel(
    const float* __restrict__ x, const float* __restrict__ W,
    const float* __restrict__ a1, const float* __restrict__ b1,
    const float* __restrict__ a2, const float* __restrict__ b2,
    unsigned short* __restrict__ h2, float* __restrict__ f1, float* __restrict__ f2,
    int N)
{
    __shared__ __align__(16) unsigned int Wt[64 * 128];   // 64 cols x 256 k bf16 = 32 KB
    __shared__ __align__(16) float xs[2][128 * 32];       // 2 x 16 KB

    const int t    = threadIdx.x;
    const int wave = t >> 6;
    const int lane = t & 63;
    const int rowB = blockIdx.x * 128;

    // stage W -> Wt[c][k] bf16, granule(8k)=16B, slot g holds global granule g^(c&7)
    for (int p = t; p < 64 * 32; p += 256) {
        int c = p & 63, g = p >> 6;
        float f[8];
#pragma unroll
        for (int j = 0; j < 8; ++j) f[j] = W[(g * 8 + j) * 64 + c];
        u32x4 d;
        d.x = cvt_pk_bf16(f[0], f[1]);
        d.y = cvt_pk_bf16(f[2], f[3]);
        d.z = cvt_pk_bf16(f[4], f[5]);
        d.w = cvt_pk_bf16(f[6], f[7]);
        int gs = g ^ (c & 7);
        *(u32x4*)&Wt[c * 128 + gs * 4] = d;
    }

    auto stage = [&](int buf, int kc) {
#pragma unroll
        for (int i = 0; i < 4; ++i) {
            int row  = i * 32 + wave * 8 + (lane >> 3);
            int g    = lane & 7;
            int srow = rowB + row; if (srow > N - 1) srow = N - 1;
            int gsw  = g ^ (row & 7);
            const float* src = x + (size_t)srow * F_IN + kc + gsw * 4;
            gload_lds16(src, &xs[buf][i * 1024 + wave * 256]);
        }
    };

    f32x4 acc[2][4];
#pragma unroll
    for (int m = 0; m < 2; ++m)
#pragma unroll
        for (int n = 0; n < 4; ++n) acc[m][n] = (f32x4){0.f, 0.f, 0.f, 0.f};

    stage(0, 0);
    asm volatile("s_waitcnt vmcnt(0)" ::: "memory");
    __syncthreads();

    for (int ks = 0; ks < 8; ++ks) {
        int cur = ks & 1;
        if (ks < 7) stage(cur ^ 1, (ks + 1) * 32);

        bf16x8 bfrag[4];
#pragma unroll
        for (int ns = 0; ns < 4; ++ns) {
            int c = ns * 16 + (lane & 15);
            int G = ks * 4 + (lane >> 4);
            u32x4 bw = *(u32x4*)&Wt[c * 128 + ((G ^ (c & 7)) << 2)];
            bfrag[ns] = __builtin_bit_cast(bf16x8, bw);
        }
#pragma unroll
        for (int ms = 0; ms < 2; ++ms) {
            int wrow = wave * 32 + ms * 16 + (lane & 15);
            int g0   = (lane >> 4) * 2;
            float4 xa = *(float4*)&xs[cur][wrow * 32 + (((g0 + 0) ^ (wrow & 7)) << 2)];
            float4 xb = *(float4*)&xs[cur][wrow * 32 + (((g0 + 1) ^ (wrow & 7)) << 2)];
            u32x4 ad;
            ad.x = cvt_pk_bf16(xa.x, xa.y);
            ad.y = cvt_pk_bf16(xa.z, xa.w);
            ad.z = cvt_pk_bf16(xb.x, xb.y);
            ad.w = cvt_pk_bf16(xb.z, xb.w);
            bf16x8 afrag = __builtin_bit_cast(bf16x8, ad);
#pragma unroll
            for (int ns = 0; ns < 4; ++ns)
                acc[ms][ns] = __builtin_amdgcn_mfma_f32_16x16x32_bf16(afrag, bfrag[ns],
                                                                      acc[ms][ns], 0, 0, 0);
        }
        asm volatile("s_waitcnt vmcnt(0)" ::: "memory");
        __syncthreads();
    }

    // epilogue: store h (bf16, RNE); fused f1/f2 (C/D: col=lane&15, row=(lane>>4)*4+r)
    float A1v[4], A2v[4];
#pragma unroll
    for (int ns = 0; ns < 4; ++ns) {
        A1v[ns] = a1[ns * 16 + (lane & 15)];
        A2v[ns] = a2[ns * 16 + (lane & 15)];
    }
    float B1 = b1[0], B2 = b2[0];
#pragma unroll
    for (int ms = 0; ms < 2; ++ms) {
#pragma unroll
        for (int r = 0; r < 4; ++r) {
            int grow = rowB + wave * 32 + ms * 16 + ((lane >> 4) << 2) + r;
            float s1 = 0.f, s2 = 0.f;
#pragma unroll
            for (int ns = 0; ns < 4; ++ns) {
                float v = acc[ms][ns][r];
                if (grow < N)
                    h2[(size_t)grow * OUT + ns * 16 + (lane & 15)] =
                        (unsigned short)(cvt_pk_bf16(v, v) & 0xffffu);
                s1 += v * A1v[ns];
                s2 += v * A2v[ns];
            }
#pragma unroll
            for (int off = 1; off < 16; off <<= 1) {
                s1 += __shfl_xor(s1, off);
                s2 += __shfl_xor(s2, off);
            }
            if ((lane & 15) == 0 && grow < N) { f1[grow] = s1 + B1; f2[grow] = s2 + B2; }
        }
    }
}

// ---------------- CSR build: count + per-edge rank (fused) ----------------
__global__ __launch_bounds__(256) void count_rank_kernel(const int* __restrict__ src,
                                                         int* __restrict__ counts,
                                                         int* __restrict__ rank, int E)
{
    int i = (blockIdx.x * 256 + threadIdx.x) * 4;
    if (i + 4 <= E) {
        int4 s = *(const int4*)&src[i];
        int4 r;
        r.x = atomicAdd(&counts[s.x], 1);
        r.y = atomicAdd(&counts[s.y], 1);
        r.z = atomicAdd(&counts[s.z], 1);
        r.w = atomicAdd(&counts[s.w], 1);
        *(int4*)&rank[i] = r;
    } else {
        for (; i < E; ++i) rank[i] = atomicAdd(&counts[src[i]], 1);
    }
}

__global__ __launch_bounds__(256) void scan_reduce_kernel(const int* __restrict__ counts,
                                                          int* __restrict__ partials, int N)
{
    int t = threadIdx.x, lane = t & 63, wave = t >> 6;
    int base = blockIdx.x * 1024 + t * 4;
    int s = 0;
#pragma unroll
    for (int i = 0; i < 4; ++i)
        if (base + i < N) s += counts[base + i];
    for (int off = 32; off > 0; off >>= 1) s += __shfl_down(s, off);
    __shared__ int wsum[4];
    if (lane == 0) wsum[wave] = s;
    __syncthreads();
    if (t == 0) partials[blockIdx.x] = wsum[0] + wsum[1] + wsum[2] + wsum[3];
}

__global__ void scan_partials_kernel(int* __restrict__ p, int n)
{
    int lane = threadIdx.x & 63;
    int run = 0;
    for (int base = 0; base < n; base += 128) {
        int o0 = (base + lane      < n) ? p[base + lane]      : 0;
        int o1 = (base + 64 + lane < n) ? p[base + 64 + lane] : 0;
        int v0 = o0, v1 = o1;
        for (int off = 1; off < 64; off <<= 1) { int u = __shfl_up(v0, off); if (lane >= off) v0 += u; }
        int tot0 = __shfl(v0, 63);
        for (int off = 1; off < 64; off <<= 1) { int u = __shfl_up(v1, off); if (lane >= off) v1 += u; }
        v1 += tot0;
        int tot1 = __shfl(v1, 63);
        if (base + lane      < n) p[base + lane]      = run + v0 - o0;
        if (base + 64 + lane < n) p[base + 64 + lane] = run + v1 - o1;
        run += tot1;
    }
}

__global__ __launch_bounds__(256) void scan_final_kernel(const int* __restrict__ counts,
                                                         const int* __restrict__ partials,
                                                         int* __restrict__ row_start, int N)
{
    int t = threadIdx.x, lane = t & 63, wave = t >> 6;
    int base = blockIdx.x * 1024 + t * 4;
    int c0 = (base + 0 < N) ? counts[base + 0] : 0;
    int c1 = (base + 1 < N) ? counts[base + 1] : 0;
    int c2 = (base + 2 < N) ? counts[base + 2] : 0;
    int c3 = (base + 3 < N) ? counts[base + 3] : 0;
    int tsum = c0 + c1 + c2 + c3;
    int incl = tsum;
    for (int off = 1; off < 64; off <<= 1) { int u = __shfl_up(incl, off); if (lane >= off) incl += u; }
    __shared__ int wtot[4];
    if (lane == 63) wtot[wave] = incl;
    __syncthreads();
    int woff = 0;
    for (int w0 = 0; w0 < wave; ++w0) woff += wtot[w0];
    int run = incl - tsum + woff + partials[blockIdx.x];
    if (base + 0 < N) { row_start[base + 0] = run; run += c0; }
    if (base + 1 < N) { row_start[base + 1] = run; run += c1; }
    if (base + 2 < N) { row_start[base + 2] = run; run += c2; }
    if (base + 3 < N) { row_start[base + 3] = run; run += c3; }
}

// ---------------- scatter: no atomics; packed {dst, f2[dst]} payload ----------------
__global__ __launch_bounds__(256) void scatter_kernel(
    const int* __restrict__ src, const int* __restrict__ dst, const int* __restrict__ rank,
    const int* __restrict__ row_start, const float* __restrict__ f2,
    unsigned long long* __restrict__ csr8, int E)
{
    int e = blockIdx.x * 256 + threadIdx.x;
    if (e >= E) return;
    int s = src[e];
    int d = dst[e];
    int pos = row_start[s] + rank[e];
    unsigned long long u = (unsigned long long)(unsigned)d |
                           ((unsigned long long)__builtin_bit_cast(unsigned, f2[d]) << 32);
    csr8[pos] = u;
}

// ---------------- online-softmax aggregation: one wave per node ----------------
__global__ __launch_bounds__(256) void aggregate_kernel(
    const unsigned short* __restrict__ h2, const float* __restrict__ f1,
    const int* __restrict__ row_start, const int* __restrict__ counts,
    const unsigned long long* __restrict__ csr8, const float* __restrict__ out_bias,
    float* __restrict__ out, int N)
{
    int gw   = (blockIdx.x * 256 + threadIdx.x) >> 6;
    int lane = threadIdx.x & 63;
    if (gw >= N) return;
    int base = row_start[gw];
    int deg  = counts[gw];
    float f1n = f1[gw];

    float m = -INFINITY, den = 0.f, acc = 0.f;
    int i = 0;
    for (; i + 4 <= deg; i += 4) {
        unsigned long long u0 = csr8[base + i + 0];
        unsigned long long u1 = csr8[base + i + 1];
        unsigned long long u2 = csr8[base + i + 2];
        unsigned long long u3 = csr8[base + i + 3];
        int d0 = (int)(unsigned)u0, d1 = (int)(unsigned)u1;
        int d2 = (int)(unsigned)u2, d3 = (int)(unsigned)u3;
        float hv0 = bf16bits_to_f32(h2[(size_t)d0 * OUT + lane]);
        float hv1 = bf16bits_to_f32(h2[(size_t)d1 * OUT + lane]);
        float hv2 = bf16bits_to_f32(h2[(size_t)d2 * OUT + lane]);
        float hv3 = bf16bits_to_f32(h2[(size_t)d3 * OUT + lane]);
        float e0 = f1n + __builtin_bit_cast(float, (unsigned)(u0 >> 32)); e0 = (e0 > 0.f) ? e0 : LEAKY * e0;
        float e1 = f1n + __builtin_bit_cast(float, (unsigned)(u1 >> 32)); e1 = (e1 > 0.f) ? e1 : LEAKY * e1;
        float e2 = f1n + __builtin_bit_cast(float, (unsigned)(u2 >> 32)); e2 = (e2 > 0.f) ? e2 : LEAKY * e2;
        float e3 = f1n + __builtin_bit_cast(float, (unsigned)(u3 >> 32)); e3 = (e3 > 0.f) ? e3 : LEAKY * e3;
        float cm = fmaxf(fmaxf(e0, e1), fmaxf(e2, e3));
        float mn = fmaxf(m, cm);
        float sc = __expf(m - mn);
        float p0 = __expf(e0 - mn);
        float p1 = __expf(e1 - mn);
        float p2 = __expf(e2 - mn);
        float p3 = __expf(e3 - mn);
        den = den * sc + (p0 + p1) + (p2 + p3);
        acc = acc * sc + p0 * hv0 + p1 * hv1 + p2 * hv2 + p3 * hv3;
        m = mn;
    }
    for (; i < deg; ++i) {
        unsigned long long u = csr8[base + i];
        int d = (int)(unsigned)u;
        float hv = bf16bits_to_f32(h2[(size_t)d * OUT + lane]);
        float e  = f1n + __builtin_bit_cast(float, (unsigned)(u >> 32));
        e = (e > 0.f) ? e : LEAKY * e;
        float mn = fmaxf(m, e);
        float sc = __expf(m - mn);
        float p  = __expf(e - mn);
        den = den * sc + p;
        acc = acc * sc + p * hv;
        m = mn;
    }
    float v = (deg > 0) ? (acc / den) : 0.f;
    v += out_bias[lane];
    out[(size_t)gw * OUT + lane] = (v > 0.f) ? v : (__expf(v) - 1.f);
}

extern "C" void kernel_launch(void* const* d_in, const int* in_sizes, int n_in,
                              void* d_out, int out_size, void* d_ws, size_t ws_size,
                              hipStream_t stream)
{
    const float* x        = (const float*)d_in[0];
    const float* W        = (const float*)d_in[1];
    const float* a1       = (const float*)d_in[2];
    const float* b1       = (const float*)d_in[3];
    const float* a2       = (const float*)d_in[4];
    const float* b2       = (const float*)d_in[5];
    const float* out_bias = (const float*)d_in[6];
    const int*   esrc     = (const int*)d_in[7];
    const int*   edst     = (const int*)d_in[8];
    const int N = in_sizes[0] / F_IN;
    const int E = in_sizes[7];
    float* out = (float*)d_out;

    char* wsp = (char*)d_ws;
    size_t off = 0;
    auto alloc = [&](size_t bytes) -> void* {
        void* p = wsp + off;
        off = (off + bytes + 255) & ~(size_t)255;
        return p;
    };
    unsigned short* h2   = (unsigned short*)alloc((size_t)N * OUT * sizeof(unsigned short));
    float* f1            = (float*)alloc((size_t)N * sizeof(float));
    float* f2            = (float*)alloc((size_t)N * sizeof(float));
    int*   counts        = (int*)alloc((size_t)N * sizeof(int));
    int*   row_start     = (int*)alloc((size_t)N * sizeof(int));
    int*   rank          = (int*)alloc((size_t)E * sizeof(int));
    int    nsb           = (N + 1023) / 1024;
    int*   partials      = (int*)alloc((size_t)nsb * sizeof(int));
    unsigned long long* csr8 = (unsigned long long*)alloc((size_t)E * sizeof(unsigned long long));

    hipMemsetAsync(counts, 0, (size_t)N * sizeof(int), stream);

    count_rank_kernel<<<(E / 4 + 255) / 256, 256, 0, stream>>>(esrc, counts, rank, E);
    scan_reduce_kernel<<<nsb, 256, 0, stream>>>(counts, partials, N);
    scan_partials_kernel<<<1, 64, 0, stream>>>(partials, nsb);
    scan_final_kernel<<<nsb, 256, 0, stream>>>(counts, partials, row_start, N);
    gemm_f12_kernel<<<(N + 127) / 128, 256, 0, stream>>>(x, W, a1, b1, a2, b2, h2, f1, f2, N);
    scatter_kernel<<<(E + 255) / 256, 256, 0, stream>>>(esrc, edst, rank, row_start, f2, csr8, E);
    aggregate_kernel<<<(N + 3) / 4, 256, 0, stream>>>(h2, f1, row_start, counts, csr8,
                                                      out_bias, out, N);
}